// Round 10
// baseline (162.773 us; speedup 1.0000x reference)
//
#include <hip/hip_runtime.h>
#include <hip/hip_bf16.h>
#include <cstdint>
#include <cstddef>

#define CIN   512
#define COUT  512
#define LLEN  2048
#define BATCH 8
#define KTAP  8
#define LPAD  (LLEN + 8)   // 8 zero halo rows at the front of each batch

typedef __bf16 bf16x8_t __attribute__((ext_vector_type(8)));
typedef float  f32x4_t  __attribute__((ext_vector_type(4)));
typedef float  f32x16_t __attribute__((ext_vector_type(16)));
typedef unsigned short u16x8_t __attribute__((ext_vector_type(8)));

__device__ __forceinline__ unsigned short f2bf(float f) {
  __bf16 h = (__bf16)f;                       // RNE fptrunc
  return __builtin_bit_cast(unsigned short, h);
}

__device__ __forceinline__ void gl2lds16(unsigned short* lds, const unsigned short* g) {
  __builtin_amdgcn_global_load_lds(
      (const __attribute__((address_space(1))) unsigned int*)g,
      (__attribute__((address_space(3))) unsigned int*)lds,
      16, 0, 0);
}

// ---------------- fused pre-pass ----------------
// blocks [0, 512): x (B,CIN,L) fp32 -> xtp (B, 8+L, CIN) bf16 transpose+cast
//   (unchanged from R8/R9).
// blocks [512, 1536): W (COUT*K, CIN) fp32 -> Wf bf16 FRAGMENT-MAJOR for the
//   32x32x16 MFMA. Lane l of fragment (mb,ks) holds
//   A[o = o128*128 + wm*64 + mb*32 + (l&31)][c = ct*64 + hg*32 + ks*16 + (l>>5)*8 + e]
//   off16B = k*32768 + o128*8192 + wm*4096 + hg*2048 + ct*256 + (mb*2+ks)*64 + lane
__global__ __launch_bounds__(256) void prepass_kernel(
    const float* __restrict__ x, unsigned short* __restrict__ xtp,
    const float4* __restrict__ W, u16x8_t* __restrict__ Wf) {
  const int bid = blockIdx.x;
  const int t   = threadIdx.x;

  if (bid >= 512) {                    // ---- W convert to 32x32 fragment layout ----
    int idx = (bid - 512) * 256 + t;   // 262144 chunks of 8 c-elems
    float4 a = W[idx * 2], b = W[idx * 2 + 1];
    u16x8_t o;
    o[0] = f2bf(a.x); o[1] = f2bf(a.y); o[2] = f2bf(a.z); o[3] = f2bf(a.w);
    o[4] = f2bf(b.x); o[5] = f2bf(b.y); o[6] = f2bf(b.z); o[7] = f2bf(b.w);
    const int row  = idx >> 6;         // k*COUT + o
    const int c8   = idx & 63;         // 8-elem c chunk: c = c8*8
    const int k    = row >> 9, oo = row & 511;
    const int o128 = oo >> 7, wm = (oo >> 6) & 1, mb = (oo >> 5) & 1, llo = oo & 31;
    const int ct   = c8 >> 3, rem = c8 & 7;
    const int hg   = rem >> 2, ks = (rem >> 1) & 1, lhi = rem & 1;
    const int lane = lhi * 32 + llo;
    const int off  = k * 32768 + o128 * 8192 + wm * 4096 + hg * 2048 +
                     ct * 256 + (mb * 2 + ks) * 64 + lane;
    Wf[off] = o;
    return;
  }

  // ---- x transpose: 64(c) x 256(l) per block ----
  __shared__ float tile[64][140];      // stride 140: 16B-aligned, 2-way banks
  const int b     = bid >> 6;          // 0..7
  const int rem   = bid & 63;
  const int c0    = (rem >> 3) * 64;   // 8 c-chunks
  const int lbase = (rem & 7) * 256;   // 8 l-chunks of 256

  if ((rem & 7) == 0 && t < 64) {      // halo zero: rows 0..7, cols c0..c0+63
    unsigned short* hp = xtp + ((size_t)b * LPAD + (t >> 3)) * CIN + c0 + (t & 7) * 8;
    *(u16x8_t*)hp = (u16x8_t){0, 0, 0, 0, 0, 0, 0, 0};
  }

#pragma unroll 1
  for (int p = 0; p < 2; ++p) {
    const int l0 = lbase + p * 128;
    {
      const int cr = t >> 2;           // 0..63
      const float* srcp = x + ((size_t)b * CIN + c0 + cr) * LLEN + l0;
#pragma unroll
      for (int i = 0; i < 8; ++i) {    // 8 independent float4 loads
        float4 v = *(const float4*)(srcp + ((t & 3) + 4 * i) * 4);
        *(float4*)&tile[cr][((t & 3) + 4 * i) * 4] = v;
      }
    }
    __syncthreads();
    {
      const int l    = t >> 1;         // 0..127
      const int cseg = (t & 1) * 32;   // 0 or 32
      unsigned short ov[32];
#pragma unroll
      for (int u = 0; u < 32; ++u) ov[u] = f2bf(tile[cseg + u][l]);
      unsigned short* dst = xtp + ((size_t)b * LPAD + 8 + l0 + l) * CIN + c0 + cseg;
      *(u16x8_t*)(dst)      = *(const u16x8_t*)&ov[0];
      *(u16x8_t*)(dst + 8)  = *(const u16x8_t*)&ov[8];
      *(u16x8_t*)(dst + 16) = *(const u16x8_t*)&ov[16];
      *(u16x8_t*)(dst + 24) = *(const u16x8_t*)&ov[24];
    }
    __syncthreads();
  }
}

// ---------------- fused conv GEMM ----------------
// R10: same shell as R9 (A global->VGPR fragment-major, B LDS dbuf + XOR
// swizzle, 8 barriers, hg c-split, XCD-bijective block swizzle) but the MFMA
// shape switches 16x16x32 -> 32x32x16: 2x FLOP/inst (8 MFMA/tap instead of
// 16), 15% higher measured ceiling (2382 vs 2075 TF), identical operand
// counts and bytes (4 A-loads + 4 ds_read_b128 per tap). k-slot placement is
// permutation-safe (full K-sum, symmetric A/B operand layouts); C/D mapping
// per measured m74/m101: col=lane&31, row=(r&3)+8*(r>>2)+4*(lane>>5).

__global__ __launch_bounds__(512, 4) void conv_gemm_kernel(
    const unsigned short* __restrict__ Wf,   // fragment-major bf16 (4 MB)
    const unsigned short* __restrict__ xtp,  // (B, LPAD, CIN) bf16
    const float* __restrict__ bias,          // (COUT)
    float* __restrict__ y)                   // (B, COUT, LLEN) fp32
{
  // Bs[2]: 2 x 136*64 bf16 = 34 KB; epilogue scratch 64 KB fp32 aliased.
  __shared__ __align__(16) unsigned char smem[65536];

  // ---- XCD-bijective block swizzle (512 blocks, 8 XCDs, 64 blocks/XCD) ----
  const int bid = blockIdx.x;                      // 0..511
  const int swz = (bid & 7) * 64 + (bid >> 3);     // XCD-contiguous chunks
  const int oy  = swz >> 7;                        // 0..3 : ONE per XCD pair
  const int rzx = swz & 127;
  const int b   = rzx >> 4;                        // 0..7 batch
  const int l0  = (rzx & 15) * 128;                // 0..15 l-tile
  const int o0  = oy * 128;

  const int t    = threadIdx.x;
  const int lane = t & 63;
  const int wid  = t >> 6;            // 0..7
  const int wm   = wid & 1;           // o half
  const int wn   = (wid >> 1) & 1;    // l half
  const int hg   = wid >> 2;          // K-half (c-chunks hg*4 .. hg*4+3)

  const int llo = lane & 31;
  const int lhi = lane >> 5;

  unsigned short* BsBuf = (unsigned short*)smem;   // [buf * 8704]

  f32x16_t acc[2][2];
#pragma unroll
  for (int i = 0; i < 2; ++i)
#pragma unroll
    for (int j = 0; j < 2; ++j)
#pragma unroll
      for (int r = 0; r < 16; ++r)
        acc[i][j][r] = 0.f;

  // B staging: rows of 64 bf16 = 8 chunks of 16 B; LDS slot s of row r holds
  // source chunk s ^ (r & 7) (swizzle applied on the SOURCE address).
  const int srow    = t >> 3;                       // 0..63 per round
  const int schunk  = (t & 7) ^ (srow & 7);         // swizzled source chunk
  const int lds_off = t * 8;                        // elements (t*16 bytes)

  const unsigned short* xb = xtp + (size_t)b * LPAD * CIN;

  auto stage_B = [&](int ct, int buf) {             // 128 rows = 2 rounds + halo
    const int c0 = ct * 64;
    const unsigned short* src = xb + (size_t)(l0 + srow) * CIN + c0 + schunk * 8;
#pragma unroll
    for (int rd = 0; rd < 2; ++rd)
      gl2lds16(BsBuf + buf * 8704 + lds_off + rd * 4096, src + (size_t)rd * 64 * CIN);
    if (t < 64) {
      const int r2  = 128 + (t >> 3);               // halo rows 128..135
      const int ch2 = (t & 7) ^ (r2 & 7);
      gl2lds16(BsBuf + buf * 8704 + 128 * 64 + t * 8,
               xb + (size_t)(l0 + r2) * CIN + c0 + ch2 * 8);
    }
  };

  const u16x8_t* Wfp = (const u16x8_t*)Wf;
  // per-wave fragment base (16B units): o128*8192 + wm*4096 + hg*2048 + lane
  const int woff = oy * 8192 + wm * 4096 + hg * 2048 + lane;

  stage_B(0, 0);
  __syncthreads();

#pragma unroll 1
  for (int ct = 0; ct < 8; ++ct) {
    if (ct + 1 < 8) stage_B(ct + 1, (ct + 1) & 1);  // in flight across 8 taps
    const unsigned short* Bc = BsBuf + (ct & 1) * 8704;
    const u16x8_t* wp = Wfp + woff + ct * 256;
#pragma unroll
    for (int k = 0; k < 8; ++k) {
      bf16x8_t af[4], bfr[4];
#pragma unroll
      for (int i = 0; i < 4; ++i)                   // i = mb*2 + ks
        af[i] = __builtin_bit_cast(bf16x8_t, wp[k * 32768 + i * 64]);
#pragma unroll
      for (int nb = 0; nb < 2; ++nb)
#pragma unroll
        for (int ks = 0; ks < 2; ++ks) {
          int row  = (8 - k) + wn * 64 + nb * 32 + llo;     // halo shift
          int slot = (hg * 4 + ks * 2 + lhi) ^ (row & 7);
          bfr[nb * 2 + ks] = *(const bf16x8_t*)(Bc + row * 64 + slot * 8);
        }
      __builtin_amdgcn_s_setprio(1);
#pragma unroll
      for (int mb = 0; mb < 2; ++mb)
#pragma unroll
        for (int nb = 0; nb < 2; ++nb)
#pragma unroll
          for (int ks = 0; ks < 2; ++ks)
            acc[mb][nb] = __builtin_amdgcn_mfma_f32_32x32x16_bf16(
                af[mb * 2 + ks], bfr[nb * 2 + ks], acc[mb][nb], 0, 0, 0);
      __builtin_amdgcn_s_setprio(0);
    }
    __syncthreads();  // one barrier per ct chunk (8 total)
  }

  // ---- cross-hg reduction through LDS (alias smem; 16 KB per (wm,wn) pair) ----
  float* red = (float*)smem + (size_t)(wn * 2 + wm) * 4096;
  if (hg == 1) {
#pragma unroll
    for (int mb = 0; mb < 2; ++mb)
#pragma unroll
      for (int nb = 0; nb < 2; ++nb)
#pragma unroll
        for (int r = 0; r < 16; ++r)
          red[((mb * 2 + nb) * 16 + r) * 64 + lane] = acc[mb][nb][r];
  }
  __syncthreads();
  if (hg == 0) {
    // epilogue: D layout col=lane&31 (=l), row=(r&3)+8*(r>>2)+4*lhi (=o)
#pragma unroll
    for (int mb = 0; mb < 2; ++mb) {
      const int o_base = o0 + wm * 64 + mb * 32;
#pragma unroll
      for (int nb = 0; nb < 2; ++nb) {
        const int l = l0 + wn * 64 + nb * 32 + llo;
#pragma unroll
        for (int r = 0; r < 16; ++r) {
          const int o = o_base + (r & 3) + 8 * (r >> 2) + 4 * lhi;
          float v = acc[mb][nb][r] + red[((mb * 2 + nb) * 16 + r) * 64 + lane];
          y[((size_t)b * COUT + o) * LLEN + l] = v + bias[o];
        }
      }
    }
  }
}

// ---------------- launch ----------------

extern "C" void kernel_launch(void* const* d_in, const int* in_sizes, int n_in,
                              void* d_out, int out_size, void* d_ws, size_t ws_size,
                              hipStream_t stream) {
  const float* x    = (const float*)d_in[0];   // (8, 512, 2048)
  const float* W    = (const float*)d_in[1];   // (4096, 512)
  const float* bias = (const float*)d_in[2];   // (512)
  float* y          = (float*)d_out;           // (8, 512, 2048)

  unsigned short* xtp = (unsigned short*)d_ws;                     // 16,842,752 B
  unsigned short* Wf  = (unsigned short*)((char*)d_ws +
                        (size_t)BATCH * LPAD * CIN * sizeof(unsigned short));

  prepass_kernel<<<512 + 1024, 256, 0, stream>>>(
      x, xtp, (const float4*)W, (u16x8_t*)Wf);
  conv_gemm_kernel<<<512, 512, 0, stream>>>(
      Wf, xtp, bias, y);
}

// Round 11
// 147.495 us; speedup vs baseline: 1.1036x; 1.1036x over previous
//
#include <hip/hip_runtime.h>
#include <hip/hip_bf16.h>
#include <cstdint>
#include <cstddef>

#define CIN   512
#define COUT  512
#define LLEN  2048
#define BATCH 8
#define KTAP  8
#define LPAD  (LLEN + 8)   // 8 zero halo rows at the front of each batch

typedef __bf16 bf16x8_t __attribute__((ext_vector_type(8)));
typedef float  f32x4_t  __attribute__((ext_vector_type(4)));
typedef unsigned short u16x8_t __attribute__((ext_vector_type(8)));

__device__ __forceinline__ unsigned short f2bf(float f) {
  __bf16 h = (__bf16)f;                       // RNE fptrunc
  return __builtin_bit_cast(unsigned short, h);
}

__device__ __forceinline__ void gl2lds16(unsigned short* lds, const unsigned short* g) {
  __builtin_amdgcn_global_load_lds(
      (const __attribute__((address_space(1))) unsigned int*)g,
      (__attribute__((address_space(3))) unsigned int*)lds,
      16, 0, 0);
}

// ---------------- fused pre-pass (R8 version -- best) ----------------
// blocks [0, 512): x (B,CIN,L) fp32 -> xtp (B, 8+L, CIN) bf16 transpose+cast.
//   64(c) x 256(l) per block, 2 phase-pairs; float4 LDS ops; stride-140 pad.
// blocks [512, 1536): W (COUT*K, CIN) fp32 -> Wf bf16 FRAGMENT-MAJOR for the
//   16x16x32 MFMA:
//   off16B = k*32768 + o128*8192 + wm*4096 + hg*2048 + ct*256 + i*64 + lane
__global__ __launch_bounds__(256) void prepass_kernel(
    const float* __restrict__ x, unsigned short* __restrict__ xtp,
    const float4* __restrict__ W, u16x8_t* __restrict__ Wf) {
  const int bid = blockIdx.x;
  const int t   = threadIdx.x;

  if (bid >= 512) {                    // ---- W convert to fragment layout ----
    int idx = (bid - 512) * 256 + t;   // 262144 chunks of 8 c-elems
    float4 a = W[idx * 2], b = W[idx * 2 + 1];
    u16x8_t o;
    o[0] = f2bf(a.x); o[1] = f2bf(a.y); o[2] = f2bf(a.z); o[3] = f2bf(a.w);
    o[4] = f2bf(b.x); o[5] = f2bf(b.y); o[6] = f2bf(b.z); o[7] = f2bf(b.w);
    const int row  = idx >> 6;         // k*COUT + o
    const int cch  = idx & 63;         // c chunk (8 elems)
    const int k    = row >> 9, oo = row & 511;
    const int o128 = oo >> 7, wm = (oo >> 6) & 1, fi = (oo >> 4) & 3, lrow = oo & 15;
    const int ct   = cch >> 3, chin = cch & 7, hg = chin >> 2, quad = chin & 3;
    const int lane = quad * 16 + lrow;
    const int off  = k * 32768 + o128 * 8192 + wm * 4096 + hg * 2048 +
                     ct * 256 + fi * 64 + lane;
    Wf[off] = o;
    return;
  }

  // ---- x transpose: 64(c) x 256(l) per block ----
  __shared__ float tile[64][140];      // stride 140: 16B-aligned, 2-way banks
  const int b     = bid >> 6;          // 0..7
  const int rem   = bid & 63;
  const int c0    = (rem >> 3) * 64;   // 8 c-chunks
  const int lbase = (rem & 7) * 256;   // 8 l-chunks of 256

  if ((rem & 7) == 0 && t < 64) {      // halo zero: rows 0..7, cols c0..c0+63
    unsigned short* hp = xtp + ((size_t)b * LPAD + (t >> 3)) * CIN + c0 + (t & 7) * 8;
    *(u16x8_t*)hp = (u16x8_t){0, 0, 0, 0, 0, 0, 0, 0};
  }

#pragma unroll 1
  for (int p = 0; p < 2; ++p) {
    const int l0 = lbase + p * 128;
    {
      const int cr = t >> 2;           // 0..63
      const float* srcp = x + ((size_t)b * CIN + c0 + cr) * LLEN + l0;
#pragma unroll
      for (int i = 0; i < 8; ++i) {    // 8 independent float4 loads
        float4 v = *(const float4*)(srcp + ((t & 3) + 4 * i) * 4);
        *(float4*)&tile[cr][((t & 3) + 4 * i) * 4] = v;
      }
    }
    __syncthreads();
    {
      const int l    = t >> 1;         // 0..127
      const int cseg = (t & 1) * 32;   // 0 or 32
      unsigned short ov[32];
#pragma unroll
      for (int u = 0; u < 32; ++u) ov[u] = f2bf(tile[cseg + u][l]);
      unsigned short* dst = xtp + ((size_t)b * LPAD + 8 + l0 + l) * CIN + c0 + cseg;
      *(u16x8_t*)(dst)      = *(const u16x8_t*)&ov[0];
      *(u16x8_t*)(dst + 8)  = *(const u16x8_t*)&ov[8];
      *(u16x8_t*)(dst + 16) = *(const u16x8_t*)&ov[16];
      *(u16x8_t*)(dst + 24) = *(const u16x8_t*)&ov[24];
    }
    __syncthreads();
  }
}

// ---------------- fused conv GEMM (R4 body -- session best, 60.2 us) ----------------
// C[o][l] (128x128 per block) = sum_k sum_c W[k*COUT+o][c] * xT[l-k][c].
// A (weights) loaded directly global->VGPR from fragment-major Wf (coalesced
// 1 KB/instr, L2-served); B in LDS, XOR-swizzled, double-buffered per ct
// chunk (8 barriers total, stage issued a full span ahead). Waves 2(o) x
// 2(l) x 2(K-half); cross-hg reduction through LDS in the epilogue.
// R10's 32x32 shape reverted: its 32-lane-row B-read pattern broke the XOR
// swizzle (4.2M bank-conflict cycles); 16-row/4-quad reads measure 0.

__global__ __launch_bounds__(512, 4) void conv_gemm_kernel(
    const unsigned short* __restrict__ Wf,   // fragment-major bf16 (4 MB)
    const unsigned short* __restrict__ xtp,  // (B, LPAD, CIN) bf16
    const float* __restrict__ bias,          // (COUT)
    float* __restrict__ y)                   // (B, COUT, LLEN) fp32
{
  // Bs[2]: 2 x 136*64 bf16 = 34 KB; epilogue scratch 64 KB fp32 aliased.
  __shared__ __align__(16) unsigned char smem[65536];

  const int t    = threadIdx.x;
  const int lane = t & 63;
  const int wid  = t >> 6;            // 0..7
  const int wm   = wid & 1;           // o half
  const int wn   = (wid >> 1) & 1;    // l half
  const int hg   = wid >> 2;          // K-half (c-chunks hg*4 .. hg*4+3)
  const int l0   = blockIdx.x * 128;
  const int o0   = blockIdx.y * 128;
  const int b    = blockIdx.z;

  const int quad = lane >> 4;
  const int lrow = lane & 15;

  unsigned short* BsBuf = (unsigned short*)smem;   // [buf * 8704]

  f32x4_t acc[4][4];
#pragma unroll
  for (int i = 0; i < 4; ++i)
#pragma unroll
    for (int j = 0; j < 4; ++j)
      acc[i][j] = (f32x4_t){0.f, 0.f, 0.f, 0.f};

  // B staging: rows of 64 bf16 = 8 chunks of 16 B; LDS slot s of row r holds
  // source chunk s ^ (r & 7) (swizzle applied on the SOURCE address).
  const int srow    = t >> 3;                       // 0..63 per round
  const int schunk  = (t & 7) ^ (srow & 7);         // swizzled source chunk
  const int lds_off = t * 8;                        // elements (t*16 bytes)

  const unsigned short* xb = xtp + (size_t)b * LPAD * CIN;

  auto stage_B = [&](int ct, int buf) {             // 128 rows = 2 rounds + halo
    const int c0 = ct * 64;
    const unsigned short* src = xb + (size_t)(l0 + srow) * CIN + c0 + schunk * 8;
#pragma unroll
    for (int rd = 0; rd < 2; ++rd)
      gl2lds16(BsBuf + buf * 8704 + lds_off + rd * 4096, src + (size_t)rd * 64 * CIN);
    if (t < 64) {
      const int r2  = 128 + (t >> 3);               // halo rows 128..135
      const int ch2 = (t & 7) ^ (r2 & 7);
      gl2lds16(BsBuf + buf * 8704 + 128 * 64 + t * 8,
               xb + (size_t)(l0 + r2) * CIN + c0 + ch2 * 8);
    }
  };

  const u16x8_t* Wfp = (const u16x8_t*)Wf;
  // per-wave fragment base (16B units): o128*8192 + wm*4096 + hg*2048 + lane
  const int woff = blockIdx.y * 8192 + wm * 4096 + hg * 2048 + lane;

  stage_B(0, 0);
  __syncthreads();

#pragma unroll 1
  for (int ct = 0; ct < 8; ++ct) {
    if (ct + 1 < 8) stage_B(ct + 1, (ct + 1) & 1);  // in flight across 8 taps
    const unsigned short* Bc = BsBuf + (ct & 1) * 8704;
    const u16x8_t* wp = Wfp + woff + ct * 256;
#pragma unroll
    for (int k = 0; k < 8; ++k) {
      bf16x8_t af[4], bfr[4];
#pragma unroll
      for (int i = 0; i < 4; ++i)
        af[i] = __builtin_bit_cast(bf16x8_t, wp[k * 32768 + i * 64]);
#pragma unroll
      for (int j = 0; j < 4; ++j) {
        int row  = (8 - k) + wn * 64 + j * 16 + lrow;   // halo shift
        int slot = (hg * 4 + quad) ^ (row & 7);
        bfr[j] = *(const bf16x8_t*)(Bc + row * 64 + slot * 8);
      }
      __builtin_amdgcn_s_setprio(1);
#pragma unroll
      for (int i = 0; i < 4; ++i)
#pragma unroll
        for (int j = 0; j < 4; ++j)
          acc[i][j] = __builtin_amdgcn_mfma_f32_16x16x32_bf16(
              af[i], bfr[j], acc[i][j], 0, 0, 0);
      __builtin_amdgcn_s_setprio(0);
    }
    __syncthreads();  // one barrier per ct chunk (8 total)
  }

  // ---- cross-hg reduction through LDS (alias smem; 16 KB per (wm,wn) pair) ----
  float* red = (float*)smem + (size_t)(wn * 2 + wm) * 4096;
  if (hg == 1) {
#pragma unroll
    for (int i = 0; i < 4; ++i)
#pragma unroll
      for (int j = 0; j < 4; ++j)
#pragma unroll
        for (int r = 0; r < 4; ++r)
          red[((i * 4 + j) * 4 + r) * 64 + lane] = acc[i][j][r];
  }
  __syncthreads();
  if (hg == 0) {
    // epilogue: D layout col = lane&15 (=l), row = quad*4+reg (=o)
#pragma unroll
    for (int i = 0; i < 4; ++i) {
      const int o_base = o0 + wm * 64 + i * 16 + quad * 4;
      const float4 bv = *(const float4*)(bias + o_base);
      const float bvr[4] = {bv.x, bv.y, bv.z, bv.w};
#pragma unroll
      for (int j = 0; j < 4; ++j) {
        const int l = l0 + wn * 64 + j * 16 + lrow;
#pragma unroll
        for (int r = 0; r < 4; ++r) {
          float v = acc[i][j][r] + red[((i * 4 + j) * 4 + r) * 64 + lane];
          y[((size_t)b * COUT + o_base + r) * LLEN + l] = v + bvr[r];
        }
      }
    }
  }
}

// ---------------- launch ----------------

extern "C" void kernel_launch(void* const* d_in, const int* in_sizes, int n_in,
                              void* d_out, int out_size, void* d_ws, size_t ws_size,
                              hipStream_t stream) {
  const float* x    = (const float*)d_in[0];   // (8, 512, 2048)
  const float* W    = (const float*)d_in[1];   // (4096, 512)
  const float* bias = (const float*)d_in[2];   // (512)
  float* y          = (float*)d_out;           // (8, 512, 2048)

  unsigned short* xtp = (unsigned short*)d_ws;                     // 16,842,752 B
  unsigned short* Wf  = (unsigned short*)((char*)d_ws +
                        (size_t)BATCH * LPAD * CIN * sizeof(unsigned short));

  prepass_kernel<<<512 + 1024, 256, 0, stream>>>(
      x, xtp, (const float4*)W, (u16x8_t*)Wf);
  conv_gemm_kernel<<<dim3(LLEN / 128, COUT / 128, BATCH), 512, 0, stream>>>(
      Wf, xtp, bias, y);
}